// Round 3
// baseline (298.921 us; speedup 1.0000x reference)
//
#include <hip/hip_runtime.h>
#include <hip/hip_cooperative_groups.h>
#include <math.h>

namespace cg = cooperative_groups;

#define KOBJ 256
#define NW   4
#define WSTR 257              // per-wave bucket stride (bank-conflict pad)
#define QMIN 0.5f
#define BETA_CLIP_C (1.0f - 1e-5f)

typedef unsigned long long u64;

// Hand-overlaid shared memory (union of the five phase layouts; max = phase A 21584 B)
#define SM_BYTES 21600

// Single cooperative kernel: 5 phases separated by grid.sync().
// grid = nbh blocks (391 for n=100000) x 256 threads; __launch_bounds__(256,2)
// guarantees 2 blocks/CU co-residency (512 >= 391). LDS 21.6KB*2 = 43KB < 160KB.
__global__ __launch_bounds__(256, 2) void fused(
    const float*  __restrict__ pred_beta,
    const float2* __restrict__ pred_ccoords,
    const float*  __restrict__ pred_energy,
    const float2* __restrict__ pred_pos,
    const float*  __restrict__ pred_time,
    const float2* __restrict__ pred_id2,
    const float*  __restrict__ t_energy,
    const float2* __restrict__ t_pos,
    const float*  __restrict__ t_time,
    const int*    __restrict__ t_idx,
    u64*    __restrict__ pk_part,   // [KOBJ][pstr]
    float*  __restrict__ cnt_part,  // [KOBJ][pstr]
    float*  __restrict__ den_part,  // [KOBJ][pstr]
    float*  __restrict__ num_part,  // [KOBJ][pstr]
    float*  __restrict__ noise_part,// [nbh]
    float4* __restrict__ objA,      // (xk, yk, qa, cnt)
    float4* __restrict__ objB,      // (pay, lb, valid, 0)
    float4* __restrict__ objC,      // (s0, valid, cnt, 0)
    float*  __restrict__ rep_part,  // [KOBJ][pstr]
    float*  __restrict__ att_part,  // [KOBJ][pstr]
    float*  __restrict__ out,
    int n, int nbh, int pstr)
{
    cg::grid_group grid = cg::this_grid();
    __shared__ __align__(16) char smraw[SM_BYTES];
    int t = threadIdx.x;
    int b = blockIdx.x;

    // ================= Phase A: per-block per-wave LDS bucket accumulation =====
    // grid=nbh blocks -> exactly ONE point per thread (no stride loop).
    {
        u64   (*spk)[WSTR]  = reinterpret_cast<u64(*)[WSTR]>(smraw);            // 8224 B
        float (*scnt)[WSTR] = reinterpret_cast<float(*)[WSTR]>(smraw + 8224);   // 4112 B
        float (*sden)[WSTR] = reinterpret_cast<float(*)[WSTR]>(smraw + 12336);  // 4112 B
        float (*snum)[WSTR] = reinterpret_cast<float(*)[WSTR]>(smraw + 16448);  // 4112 B
        float  *snoise      = reinterpret_cast<float*>(smraw + 20560);          // 1024 B
        int w = t >> 6;
        for (int i = t; i < NW * WSTR; i += 256) {
            ((u64*)spk)[i] = 0;
            ((float*)scnt)[i] = 0.f;
            ((float*)sden)[i] = 0.f;
            ((float*)snum)[i] = 0.f;
        }
        __syncthreads();

        float noise = 0.0f;
        int i = b * 256 + t;
        if (i < n) {
            int tid = t_idx[i];
            float braw = pred_beta[i];
            float beta = fminf(fmaxf(braw, 0.0f), BETA_CLIP_C);
            if (tid >= 0) {
                atomicAdd(&scnt[w][tid], 1.0f);
                u64 key = ((u64)__float_as_uint(beta) << 32) |
                          (u64)(0x7FFFFFFFu - (unsigned)i);   // max beta, tie -> lowest index
                atomicMax(&spk[w][tid], key);
                float te = t_energy[i];
                float ew = (te > 10.0f) ? 1.0f : fmaxf(0.0f, (te - 0.5f) / 9.5f);
                float de = te - pred_energy[i];
                float el = de * de / (te + 1.0f);
                float2 tp = t_pos[i];
                float2 pp = pred_pos[i];
                float dpx = tp.x - pp.x, dpy = tp.y - pp.y;
                float pl = (dpx * dpx + dpy * dpy) * 0.01f;
                float dt = t_time[i] - pred_time[i];
                float tl = dt * dt;
                float2 id0 = pred_id2[3 * i];
                float2 id1 = pred_id2[3 * i + 1];
                float2 id2 = pred_id2[3 * i + 2];
                float cs = id0.x * id0.x + id0.y * id0.y + id1.x * id1.x +
                           id1.y * id1.y + id2.x * id2.x + id2.y * id2.y;
                cs *= (1e-8f / 6.0f);
                float mask = (braw < 0.1f) ? 0.0f : 1.0f;  // PAYLOAD_BETA_CLIP on raw beta
                float wgt = mask * ew * beta;
                atomicAdd(&sden[w][tid], beta);
                atomicAdd(&snum[w][tid], (el + pl + tl + cs) * wgt);
            } else {
                noise = beta;
            }
        }
        __syncthreads();
        // fold 4 wave-buckets -> 1 (stride-1 reads, conflict-free)
        u64 pk = spk[0][t];
        { u64 q = spk[1][t]; if (q > pk) pk = q; }
        { u64 q = spk[2][t]; if (q > pk) pk = q; }
        { u64 q = spk[3][t]; if (q > pk) pk = q; }
        float cnt = scnt[0][t] + scnt[1][t] + scnt[2][t] + scnt[3][t];
        float den = sden[0][t] + sden[1][t] + sden[2][t] + sden[3][t];
        float num = snum[0][t] + snum[1][t] + snum[2][t] + snum[3][t];
        int o = t * pstr + b;
        pk_part[o]  = pk;
        cnt_part[o] = cnt;
        den_part[o] = den;
        num_part[o] = num;
        snoise[t] = noise;
        __syncthreads();
        for (int s = 128; s > 0; s >>= 1) {
            if (t < s) snoise[t] += snoise[t + s];
            __syncthreads();
        }
        if (t == 0) noise_part[b] = snoise[0];
    }
    grid.sync();

    // ================= Phase B: object merge (blocks 0..KOBJ-1) ================
    if (b < KOBJ) {
        u64   *spk  = reinterpret_cast<u64*>(smraw);            // 2048 B
        float *scnt = reinterpret_cast<float*>(smraw + 2048);
        float *sden = reinterpret_cast<float*>(smraw + 3072);
        float *snum = reinterpret_cast<float*>(smraw + 4096);
        u64 pk = 0;
        float cnt = 0.f, den = 0.f, num = 0.f;
        for (int j = t; j < nbh; j += 256) {       // coalesced row reads
            int o = b * pstr + j;
            u64 q = pk_part[o]; if (q > pk) pk = q;
            cnt += cnt_part[o]; den += den_part[o]; num += num_part[o];
        }
        spk[t] = pk; scnt[t] = cnt; sden[t] = den; snum[t] = num;
        __syncthreads();
        for (int s = 128; s > 0; s >>= 1) {
            if (t < s) {
                u64 p2 = spk[t + s]; if (p2 > spk[t]) spk[t] = p2;
                scnt[t] += scnt[t + s];
                sden[t] += sden[t + s];
                snum[t] += snum[t + s];
            }
            __syncthreads();
        }
        if (t == 0) {
            float cs = scnt[0];
            bool valid = cs > 0.f;
            float xk = 0.f, yk = 0.f, qa = 0.f, lb = 0.f, pay = 0.f;
            if (valid) {
                u64 p = spk[0];
                unsigned a = 0x7FFFFFFFu - (unsigned)(p & 0xFFFFFFFFull);
                float ba = __uint_as_float((unsigned)(p >> 32));
                float2 cc = pred_ccoords[a];
                xk = cc.x; yk = cc.y;
                float at = atanhf(ba);
                qa = at * at + QMIN;
                lb = 1.0f - ba;
                pay = snum[0] / fmaxf(sden[0], 1e-6f);
            }
            objA[b] = make_float4(xk, yk, qa, cs);
            objB[b] = make_float4(pay, lb, valid ? 1.f : 0.f, 0.f);
        }
    }
    grid.sync();

    // ================= Phase C: N x K repulsion (8-op loop) + O(N) correction ==
    {
        float4 *pts   = reinterpret_cast<float4*>(smraw);        // 4096 B
        float  *corrR = reinterpret_cast<float*>(smraw + 4096);  // 1024 B
        float  *corrA = reinterpret_cast<float*>(smraw + 5120);  // 1024 B
        corrR[t] = 0.f;
        corrA[t] = 0.f;
        int p = b * 256 + t;
        float4 pt;
        if (p < n) {
            float beta = fminf(fmaxf(pred_beta[p], 0.0f), BETA_CLIP_C);
            float at = atanhf(beta);
            float2 cc = pred_ccoords[p];
            pt = make_float4(cc.x, cc.y, at * at + QMIN, __int_as_float(t_idx[p]));
        } else {
            pt = make_float4(0.f, 0.f, 0.f, __int_as_float(-2));  // q=0 => inert
        }
        pts[t] = pt;
        float4 oa = objA[t];
        float xk = oa.x, yk = oa.y;
        __syncthreads();   // covers corr zeroing + pts store

        // own-pair correction: att_k = sum_{i in k} d2(i,x_k)*q_i (attraction numerator);
        // corrR removes the own-pair h*q the unconditional loop adds.
        int tid = __float_as_int(pt.w);
        if (tid >= 0) {
            float4 ok = objA[tid];                         // 4 KB table, L1-hot
            float dx = pt.x - ok.x, dy = pt.y - ok.y;
            float d2 = fmaf(dy, dy, fmaf(dx, dx, 1e-6f));  // eps folded (accepted numerics)
            float r = __builtin_amdgcn_sqrtf(d2);
            float h = fmaxf(0.0f, 1.0f - r);
            atomicAdd(&corrA[tid], d2 * pt.z);
            atomicAdd(&corrR[tid], h * pt.z);
        }

        float rep = 0.f;
        #pragma unroll 8
        for (int j = 0; j < 256; ++j) {
            float4 s = pts[j];                    // wave-uniform address -> bank broadcast
            float dx = s.x - xk, dy = s.y - yk;
            float d2 = fmaf(dy, dy, fmaf(dx, dx, 1e-6f));
            float r = __builtin_amdgcn_sqrtf(d2);
            float h = fmaxf(0.0f, 1.0f - r);
            rep = fmaf(h, s.z, rep);              // unconditional; own pairs removed via corrR
        }
        __syncthreads();   // all correction atomics visible
        int o = t * pstr + b;
        rep_part[o] = rep - corrR[t];
        att_part[o] = corrA[t];
    }
    grid.sync();

    // ================= Phase D: per-object reduce of heavy partials ============
    if (b < KOBJ) {
        float *srep = reinterpret_cast<float*>(smraw);           // 1024 B
        float *satt = reinterpret_cast<float*>(smraw + 1024);    // 1024 B
        float rep = 0.f, att = 0.f;
        for (int j = t; j < nbh; j += 256) {       // coalesced row reads
            int o = b * pstr + j;
            rep += rep_part[o];
            att += att_part[o];
        }
        srep[t] = rep; satt[t] = att;
        __syncthreads();
        for (int s = 128; s > 0; s >>= 1) {
            if (t < s) { srep[t] += srep[t + s]; satt[t] += satt[t + s]; }
            __syncthreads();
        }
        if (t == 0) {
            float4 a  = objA[b];
            float4 b4 = objB[b];
            float cnt = a.w, qa = a.z, valid = b4.z;
            float vatt = valid * satt[0] * qa / fmaxf(cnt, 1.0f);
            float vrep = valid * srep[0] * qa / fmaxf((float)n - cnt, 1.0f);
            objC[b] = make_float4(vatt + vrep + b4.y + b4.x, valid, cnt, 0.f);
        }
    }
    grid.sync();

    // ================= Phase E: scalar finish (block 0) ========================
    if (b == 0) {
        float4 *sred = reinterpret_cast<float4*>(smraw);         // 4096 B
        float4 c = objC[t];
        float noi = 0.f;
        for (int j = t; j < nbh; j += 256) noi += noise_part[j];
        c.w = noi;
        sred[t] = c;
        __syncthreads();
        for (int s = 128; s > 0; s >>= 1) {
            if (t < s) {
                float4 x = sred[t], y = sred[t + s];
                sred[t] = make_float4(x.x + y.x, x.y + y.y, x.z + y.z, x.w + y.w);
            }
            __syncthreads();
        }
        if (t == 0) {
            float4 r = sred[0];
            float nv = fmaxf(r.y, 1.0f);                    // n_valid
            float nnoise = fmaxf((float)n - r.z, 1.0f);     // noise count
            out[0] = r.x / nv + r.w / nnoise;
        }
    }
}

extern "C" void kernel_launch(void* const* d_in, const int* in_sizes, int n_in,
                              void* d_out, int out_size, void* d_ws, size_t ws_size,
                              hipStream_t stream) {
    const float*  pred_beta    = (const float*)d_in[0];
    const float2* pred_ccoords = (const float2*)d_in[1];
    const float*  pred_energy  = (const float*)d_in[2];
    const float2* pred_pos     = (const float2*)d_in[3];
    const float*  pred_time    = (const float*)d_in[4];
    const float2* pred_id2     = (const float2*)d_in[5];
    const float*  t_energy     = (const float*)d_in[6];
    const float2* t_pos        = (const float2*)d_in[7];
    const float*  t_time       = (const float*)d_in[8];
    const int*    t_idx        = (const int*)d_in[10];
    int n = in_sizes[0];
    int nbh = (n + 255) / 256;          // 391 for n=100000 (one point per thread)
    int pstr = (nbh + 8) & ~7;          // padded row stride (392)

    // workspace carve (16B-aligned)
    char* base = (char*)d_ws;
    size_t off = 0;
    u64*    pk_part    = (u64*)   (base + off); off += (size_t)KOBJ * pstr * 8;   // ~800 KB
    float*  cnt_part   = (float*) (base + off); off += (size_t)KOBJ * pstr * 4;   // ~400 KB
    float*  den_part   = (float*) (base + off); off += (size_t)KOBJ * pstr * 4;
    float*  num_part   = (float*) (base + off); off += (size_t)KOBJ * pstr * 4;
    float*  noise_part = (float*) (base + off); off += (size_t)((nbh + 15) & ~15) * 4;
    float4* objA       = (float4*)(base + off); off += KOBJ * 16;
    float4* objB       = (float4*)(base + off); off += KOBJ * 16;
    float4* objC       = (float4*)(base + off); off += KOBJ * 16;
    float*  rep_part   = (float*) (base + off); off += (size_t)KOBJ * pstr * 4;
    float*  att_part   = (float*) (base + off); off += (size_t)KOBJ * pstr * 4;
    float*  outp       = (float*)d_out;

    void* args[] = {
        (void*)&pred_beta, (void*)&pred_ccoords, (void*)&pred_energy, (void*)&pred_pos,
        (void*)&pred_time, (void*)&pred_id2, (void*)&t_energy, (void*)&t_pos,
        (void*)&t_time, (void*)&t_idx,
        (void*)&pk_part, (void*)&cnt_part, (void*)&den_part, (void*)&num_part,
        (void*)&noise_part, (void*)&objA, (void*)&objB, (void*)&objC,
        (void*)&rep_part, (void*)&att_part, (void*)&outp,
        (void*)&n, (void*)&nbh, (void*)&pstr
    };
    hipLaunchCooperativeKernel((const void*)fused, dim3(nbh), dim3(256), args, 0, stream);
}

// Round 4
// 108.076 us; speedup vs baseline: 2.7658x; 2.7658x over previous
//
#include <hip/hip_runtime.h>
#include <math.h>

#define KOBJ 256
#define B1   256              // partial-accumulator blocks
#define NW   4                // waves per block
#define WSTR 257              // per-wave bucket stride (bank-conflict pad)
#define QMIN 0.5f
#define BETA_CLIP_C (1.0f - 1e-5f)

typedef unsigned long long u64;

// ---------------- Kernel A: per-block LDS accumulation with PER-WAVE buckets
// (removes same-address inter-wave atomic serialization), k-major partial writes.
__global__ __launch_bounds__(256) void partials(
    const float*  __restrict__ pred_beta,
    const float*  __restrict__ pred_energy,
    const float2* __restrict__ pred_pos,
    const float*  __restrict__ pred_time,
    const float2* __restrict__ pred_id2,
    const float*  __restrict__ t_energy,
    const float2* __restrict__ t_pos,
    const float*  __restrict__ t_time,
    const int*    __restrict__ t_idx,
    u64*    __restrict__ pk_part,   // [K][B1]
    float*  __restrict__ cnt_part,  // [K][B1]
    float*  __restrict__ den_part,  // [K][B1]
    float*  __restrict__ num_part,  // [K][B1]
    float*  __restrict__ noise_part,// [B1]
    int n)
{
    __shared__ u64   spk[NW][WSTR];                   // 8.2 KB
    __shared__ float scnt[NW][WSTR], sden[NW][WSTR], snum[NW][WSTR]; // 12.3 KB
    __shared__ float snoise[256];
    int t = threadIdx.x;
    int b = blockIdx.x;
    int w = t >> 6;
    for (int i = t; i < NW * WSTR; i += 256) {
        ((u64*)spk)[i] = 0;
        ((float*)scnt)[i] = 0.f;
        ((float*)sden)[i] = 0.f;
        ((float*)snum)[i] = 0.f;
    }
    __syncthreads();

    float noise = 0.0f;
    for (int i = b * 256 + t; i < n; i += B1 * 256) {
        int tid = t_idx[i];
        float braw = pred_beta[i];
        float beta = fminf(fmaxf(braw, 0.0f), BETA_CLIP_C);
        if (tid >= 0) {
            atomicAdd(&scnt[w][tid], 1.0f);
            u64 key = ((u64)__float_as_uint(beta) << 32) |
                      (u64)(0x7FFFFFFFu - (unsigned)i);   // max beta, tie -> lowest index
            atomicMax(&spk[w][tid], key);
            float te = t_energy[i];
            float ew = (te > 10.0f) ? 1.0f : fmaxf(0.0f, (te - 0.5f) / 9.5f);
            float de = te - pred_energy[i];
            float el = de * de / (te + 1.0f);
            float2 tp = t_pos[i];
            float2 pp = pred_pos[i];
            float dpx = tp.x - pp.x, dpy = tp.y - pp.y;
            float pl = (dpx * dpx + dpy * dpy) * 0.01f;
            float dt = t_time[i] - pred_time[i];
            float tl = dt * dt;
            float2 id0 = pred_id2[3 * i];
            float2 id1 = pred_id2[3 * i + 1];
            float2 id2 = pred_id2[3 * i + 2];
            float cs = id0.x * id0.x + id0.y * id0.y + id1.x * id1.x +
                       id1.y * id1.y + id2.x * id2.x + id2.y * id2.y;
            cs *= (1e-8f / 6.0f);
            float mask = (braw < 0.1f) ? 0.0f : 1.0f;  // PAYLOAD_BETA_CLIP on raw beta
            float wgt = mask * ew * beta;
            atomicAdd(&sden[w][tid], beta);
            atomicAdd(&snum[w][tid], (el + pl + tl + cs) * wgt);
        } else {
            noise += beta;
        }
    }
    __syncthreads();
    // fold 4 wave-buckets -> 1 (stride-1 reads, conflict-free)
    u64 pk = spk[0][t];
    { u64 q = spk[1][t]; if (q > pk) pk = q; }
    { u64 q = spk[2][t]; if (q > pk) pk = q; }
    { u64 q = spk[3][t]; if (q > pk) pk = q; }
    float cnt = scnt[0][t] + scnt[1][t] + scnt[2][t] + scnt[3][t];
    float den = sden[0][t] + sden[1][t] + sden[2][t] + sden[3][t];
    float num = snum[0][t] + snum[1][t] + snum[2][t] + snum[3][t];
    int o = t * B1 + b;
    pk_part[o]  = pk;
    cnt_part[o] = cnt;
    den_part[o] = den;
    num_part[o] = num;
    snoise[t] = noise;
    __syncthreads();
    for (int s = 128; s > 0; s >>= 1) {
        if (t < s) snoise[t] += snoise[t + s];
        __syncthreads();
    }
    if (t == 0) noise_part[b] = snoise[0];
}

// ---------------- Kernel B: one block per object; coalesced row reduce.
// Also zeroes the heavy-phase global accumulators (kernel-boundary ordered,
// so no separate init node is needed despite workspace poisoning).
__global__ __launch_bounds__(256) void merge(
    const float2* __restrict__ pred_ccoords,
    const u64*    __restrict__ pk_part,
    const float*  __restrict__ cnt_part,
    const float*  __restrict__ den_part,
    const float*  __restrict__ num_part,
    float4* __restrict__ objA,   // (xk, yk, qa, cnt)
    float4* __restrict__ objB,   // (pay, lb, valid, 0)
    float*  __restrict__ rep_obj,// [KOBJ] zeroed here, accumulated by heavy
    float*  __restrict__ att_obj)// [KOBJ]
{
    __shared__ u64   spk[256];
    __shared__ float scnt[256], sden[256], snum[256];
    int k = blockIdx.x;
    int b = threadIdx.x;
    if (b == 0) { rep_obj[k] = 0.f; att_obj[k] = 0.f; }
    int o = k * B1 + b;
    u64 pk = pk_part[o];
    float cnt = cnt_part[o];
    float den = den_part[o];
    float nsum = num_part[o];
    spk[b] = pk; scnt[b] = cnt; sden[b] = den; snum[b] = nsum;
    __syncthreads();
    for (int s = 128; s > 0; s >>= 1) {
        if (b < s) {
            u64 p = spk[b + s]; if (p > spk[b]) spk[b] = p;
            scnt[b] += scnt[b + s];
            sden[b] += sden[b + s];
            snum[b] += snum[b + s];
        }
        __syncthreads();
    }
    if (b == 0) {
        float cs = scnt[0];
        bool valid = cs > 0.f;
        float xk = 0.f, yk = 0.f, qa = 0.f, lb = 0.f, pay = 0.f;
        if (valid) {
            u64 p = spk[0];
            unsigned a = 0x7FFFFFFFu - (unsigned)(p & 0xFFFFFFFFull);
            float ba = __uint_as_float((unsigned)(p >> 32));
            float2 cc = pred_ccoords[a];
            xk = cc.x; yk = cc.y;
            float at = atanhf(ba);
            qa = at * at + QMIN;
            lb = 1.0f - ba;
            pay = snum[0] / fmaxf(sden[0], 1e-6f);
        }
        objA[k] = make_float4(xk, yk, qa, cs);
        objB[k] = make_float4(pay, lb, valid ? 1.f : 0.f, 0.f);
    }
}

// ---------------- Kernel C (R0-proven 12-op loop): N x K hinge/attraction.
// Output folded per object via fire-and-forget atomicAdd (512 addresses,
// nbh adds each, addresses differ per lane -> no wave serialization).
__global__ __launch_bounds__(256) void heavy(
    const float*  __restrict__ pred_beta,
    const float2* __restrict__ pred_ccoords,
    const int*    __restrict__ t_idx,
    const float4* __restrict__ objA,
    float* __restrict__ rep_obj,   // [KOBJ]
    float* __restrict__ att_obj,   // [KOBJ]
    int n)
{
    __shared__ float4 pts[256];
    int t = threadIdx.x;
    int p = blockIdx.x * 256 + t;
    float4 pt;
    if (p < n) {
        float beta = fminf(fmaxf(pred_beta[p], 0.0f), BETA_CLIP_C);
        float at = atanhf(beta);
        float2 cc = pred_ccoords[p];
        pt = make_float4(cc.x, cc.y, at * at + QMIN, __int_as_float(t_idx[p]));
    } else {
        pt = make_float4(0.f, 0.f, 0.f, __int_as_float(-2));  // q=0 => inert
    }
    pts[t] = pt;
    float4 oa = objA[t];
    float xk = oa.x, yk = oa.y;
    __syncthreads();
    float rep = 0.f, att = 0.f;
    #pragma unroll 8
    for (int j = 0; j < 256; ++j) {
        float4 s = pts[j];                    // wave-uniform address -> bank broadcast
        float dx = s.x - xk, dy = s.y - yk;
        float d2 = fmaf(dy, dy, fmaf(dx, dx, 1e-6f));  // eps folded (att err ~1e-6*qq)
        float r = __builtin_amdgcn_sqrtf(d2);
        float h = fmaxf(0.0f, 1.0f - r);
        bool own = (__float_as_int(s.w) == t);
        rep = fmaf(own ? 0.0f : h,  s.z, rep);
        att = fmaf(own ? d2 : 0.0f, s.z, att);
    }
    atomicAdd(&rep_obj[t], rep);
    atomicAdd(&att_obj[t], att);
}

// ---------------- Kernel D: single-block finish (per-object s0 inline +
// deterministic float4 tree reduce; replaces final1+final2).
__global__ __launch_bounds__(256) void finalk(
    const float4* __restrict__ objA,
    const float4* __restrict__ objB,
    const float*  __restrict__ rep_obj,
    const float*  __restrict__ att_obj,
    const float*  __restrict__ noise_part,
    float* __restrict__ out, int n)
{
    __shared__ float4 sred[256];
    int t = threadIdx.x;
    float4 a  = objA[t];
    float4 b4 = objB[t];
    float cnt = a.w, qa = a.z, valid = b4.z;
    float vatt = valid * att_obj[t] * qa / fmaxf(cnt, 1.0f);
    float vrep = valid * rep_obj[t] * qa / fmaxf((float)n - cnt, 1.0f);
    float s0 = vatt + vrep + b4.y + b4.x;
    sred[t] = make_float4(s0, valid, cnt, noise_part[t]);
    __syncthreads();
    for (int s = 128; s > 0; s >>= 1) {
        if (t < s) {
            float4 x = sred[t], y = sred[t + s];
            sred[t] = make_float4(x.x + y.x, x.y + y.y, x.z + y.z, x.w + y.w);
        }
        __syncthreads();
    }
    if (t == 0) {
        float4 r = sred[0];
        float nv = fmaxf(r.y, 1.0f);                    // n_valid
        float nnoise = fmaxf((float)n - r.z, 1.0f);     // noise count
        out[0] = r.x / nv + r.w / nnoise;
    }
}

extern "C" void kernel_launch(void* const* d_in, const int* in_sizes, int n_in,
                              void* d_out, int out_size, void* d_ws, size_t ws_size,
                              hipStream_t stream) {
    const float*  pred_beta    = (const float*)d_in[0];
    const float2* pred_ccoords = (const float2*)d_in[1];
    const float*  pred_energy  = (const float*)d_in[2];
    const float2* pred_pos     = (const float2*)d_in[3];
    const float*  pred_time    = (const float*)d_in[4];
    const float2* pred_id2     = (const float2*)d_in[5];
    const float*  t_energy     = (const float*)d_in[6];
    const float2* t_pos        = (const float2*)d_in[7];
    const float*  t_time       = (const float*)d_in[8];
    const int*    t_idx        = (const int*)d_in[10];
    int n = in_sizes[0];
    int nbh = (n + 255) / 256;          // 391 for n=100000

    // workspace carve (16B-aligned)
    char* base = (char*)d_ws;
    size_t off = 0;
    u64*    pk_part    = (u64*)   (base + off); off += (size_t)KOBJ * B1 * 8;    // 512 KB
    float*  cnt_part   = (float*) (base + off); off += (size_t)KOBJ * B1 * 4;    // 256 KB
    float*  den_part   = (float*) (base + off); off += (size_t)KOBJ * B1 * 4;    // 256 KB
    float*  num_part   = (float*) (base + off); off += (size_t)KOBJ * B1 * 4;    // 256 KB
    float*  noise_part = (float*) (base + off); off += 256 * 4;
    float4* objA       = (float4*)(base + off); off += KOBJ * 16;
    float4* objB       = (float4*)(base + off); off += KOBJ * 16;
    float*  rep_obj    = (float*) (base + off); off += KOBJ * 4;
    float*  att_obj    = (float*) (base + off); off += KOBJ * 4;

    partials<<<B1, 256, 0, stream>>>(pred_beta, pred_energy, pred_pos, pred_time,
                                     pred_id2, t_energy, t_pos, t_time, t_idx,
                                     pk_part, cnt_part, den_part, num_part, noise_part, n);
    merge<<<KOBJ, 256, 0, stream>>>(pred_ccoords, pk_part, cnt_part, den_part, num_part,
                                    objA, objB, rep_obj, att_obj);
    heavy<<<nbh, 256, 0, stream>>>(pred_beta, pred_ccoords, t_idx, objA,
                                   rep_obj, att_obj, n);
    finalk<<<1, 256, 0, stream>>>(objA, objB, rep_obj, att_obj, noise_part,
                                  (float*)d_out, n);
}

// Round 5
// 105.186 us; speedup vs baseline: 2.8418x; 1.0275x over previous
//
#include <hip/hip_runtime.h>
#include <hip/hip_bf16.h>
#include <math.h>

#define KOBJ 256
#define B1   256              // partial-accumulator blocks
#define NW   4                // waves per block
#define WSTR 257              // per-wave bucket stride (bank-conflict pad)
#define QMIN 0.5f
#define BETA_CLIP_C (1.0f - 1e-5f)

typedef unsigned long long u64;

// ---------------- Kernel A: per-block LDS accumulation with PER-WAVE buckets
// (removes same-address inter-wave atomic serialization), k-major partial writes.
__global__ __launch_bounds__(256) void partials(
    const float*  __restrict__ pred_beta,
    const float*  __restrict__ pred_energy,
    const float2* __restrict__ pred_pos,
    const float*  __restrict__ pred_time,
    const float2* __restrict__ pred_id2,
    const float*  __restrict__ t_energy,
    const float2* __restrict__ t_pos,
    const float*  __restrict__ t_time,
    const int*    __restrict__ t_idx,
    u64*    __restrict__ pk_part,   // [K][B1]
    float*  __restrict__ cnt_part,  // [K][B1]
    float*  __restrict__ den_part,  // [K][B1]
    float*  __restrict__ num_part,  // [K][B1]
    float*  __restrict__ noise_part,// [B1]
    int n)
{
    __shared__ u64   spk[NW][WSTR];                   // 8.2 KB
    __shared__ float scnt[NW][WSTR], sden[NW][WSTR], snum[NW][WSTR]; // 12.3 KB
    __shared__ float snoise[256];
    int t = threadIdx.x;
    int b = blockIdx.x;
    int w = t >> 6;
    for (int i = t; i < NW * WSTR; i += 256) {
        ((u64*)spk)[i] = 0;
        ((float*)scnt)[i] = 0.f;
        ((float*)sden)[i] = 0.f;
        ((float*)snum)[i] = 0.f;
    }
    __syncthreads();

    float noise = 0.0f;
    for (int i = b * 256 + t; i < n; i += B1 * 256) {
        int tid = t_idx[i];
        float braw = pred_beta[i];
        float beta = fminf(fmaxf(braw, 0.0f), BETA_CLIP_C);
        if (tid >= 0) {
            atomicAdd(&scnt[w][tid], 1.0f);
            u64 key = ((u64)__float_as_uint(beta) << 32) |
                      (u64)(0x7FFFFFFFu - (unsigned)i);   // max beta, tie -> lowest index
            atomicMax(&spk[w][tid], key);
            float te = t_energy[i];
            float ew = (te > 10.0f) ? 1.0f : fmaxf(0.0f, (te - 0.5f) / 9.5f);
            float de = te - pred_energy[i];
            float el = de * de / (te + 1.0f);
            float2 tp = t_pos[i];
            float2 pp = pred_pos[i];
            float dpx = tp.x - pp.x, dpy = tp.y - pp.y;
            float pl = (dpx * dpx + dpy * dpy) * 0.01f;
            float dt = t_time[i] - pred_time[i];
            float tl = dt * dt;
            float2 id0 = pred_id2[3 * i];
            float2 id1 = pred_id2[3 * i + 1];
            float2 id2 = pred_id2[3 * i + 2];
            float cs = id0.x * id0.x + id0.y * id0.y + id1.x * id1.x +
                       id1.y * id1.y + id2.x * id2.x + id2.y * id2.y;
            cs *= (1e-8f / 6.0f);
            float mask = (braw < 0.1f) ? 0.0f : 1.0f;  // PAYLOAD_BETA_CLIP on raw beta
            float wgt = mask * ew * beta;
            atomicAdd(&sden[w][tid], beta);
            atomicAdd(&snum[w][tid], (el + pl + tl + cs) * wgt);
        } else {
            noise += beta;
        }
    }
    __syncthreads();
    // fold 4 wave-buckets -> 1 (stride-1 reads, conflict-free)
    u64 pk = spk[0][t];
    { u64 q = spk[1][t]; if (q > pk) pk = q; }
    { u64 q = spk[2][t]; if (q > pk) pk = q; }
    { u64 q = spk[3][t]; if (q > pk) pk = q; }
    float cnt = scnt[0][t] + scnt[1][t] + scnt[2][t] + scnt[3][t];
    float den = sden[0][t] + sden[1][t] + sden[2][t] + sden[3][t];
    float num = snum[0][t] + snum[1][t] + snum[2][t] + snum[3][t];
    int o = t * B1 + b;
    pk_part[o]  = pk;
    cnt_part[o] = cnt;
    den_part[o] = den;
    num_part[o] = num;
    snoise[t] = noise;
    __syncthreads();
    for (int s = 128; s > 0; s >>= 1) {
        if (t < s) snoise[t] += snoise[t + s];
        __syncthreads();
    }
    if (t == 0) noise_part[b] = snoise[0];
}

// ---------------- Kernel B: one block per object; coalesced row reduce
__global__ __launch_bounds__(256) void merge(
    const float2* __restrict__ pred_ccoords,
    const u64*    __restrict__ pk_part,
    const float*  __restrict__ cnt_part,
    const float*  __restrict__ den_part,
    const float*  __restrict__ num_part,
    float4* __restrict__ objA,   // (xk, yk, qa, cnt)
    float4* __restrict__ objB)   // (pay, lb, valid, 0)
{
    __shared__ u64   spk[256];
    __shared__ float scnt[256], sden[256], snum[256];
    int k = blockIdx.x;
    int b = threadIdx.x;
    int o = k * B1 + b;
    u64 pk = pk_part[o];
    float cnt = cnt_part[o];
    float den = den_part[o];
    float nsum = num_part[o];
    spk[b] = pk; scnt[b] = cnt; sden[b] = den; snum[b] = nsum;
    __syncthreads();
    for (int s = 128; s > 0; s >>= 1) {
        if (b < s) {
            u64 p = spk[b + s]; if (p > spk[b]) spk[b] = p;
            scnt[b] += scnt[b + s];
            sden[b] += sden[b + s];
            snum[b] += snum[b + s];
        }
        __syncthreads();
    }
    if (b == 0) {
        float cs = scnt[0];
        bool valid = cs > 0.f;
        float xk = 0.f, yk = 0.f, qa = 0.f, lb = 0.f, pay = 0.f;
        if (valid) {
            u64 p = spk[0];
            unsigned a = 0x7FFFFFFFu - (unsigned)(p & 0xFFFFFFFFull);
            float ba = __uint_as_float((unsigned)(p >> 32));
            float2 cc = pred_ccoords[a];
            xk = cc.x; yk = cc.y;
            float at = atanhf(ba);
            qa = at * at + QMIN;
            lb = 1.0f - ba;
            pay = snum[0] / fmaxf(sden[0], 1e-6f);
        }
        objA[k] = make_float4(xk, yk, qa, cs);
        objB[k] = make_float4(pay, lb, valid ? 1.f : 0.f, 0.f);
    }
}

// ---------------- Kernel C (R8-proven): N x K hinge/attraction; k-major partial writes
__global__ __launch_bounds__(256) void heavy(
    const float*  __restrict__ pred_beta,
    const float2* __restrict__ pred_ccoords,
    const int*    __restrict__ t_idx,
    const float4* __restrict__ objA,
    float* __restrict__ rep_part,   // [K][hstr]
    float* __restrict__ att_part,   // [K][hstr]
    int n, int hstr)
{
    __shared__ float4 pts[256];
    int t = threadIdx.x;
    int p = blockIdx.x * 256 + t;
    float4 pt;
    if (p < n) {
        float beta = fminf(fmaxf(pred_beta[p], 0.0f), BETA_CLIP_C);
        float at = atanhf(beta);
        float2 cc = pred_ccoords[p];
        pt = make_float4(cc.x, cc.y, at * at + QMIN, __int_as_float(t_idx[p]));
    } else {
        pt = make_float4(0.f, 0.f, 0.f, __int_as_float(-2));  // q=0 => inert
    }
    pts[t] = pt;
    float4 oa = objA[t];
    float xk = oa.x, yk = oa.y;
    __syncthreads();
    float rep = 0.f, att = 0.f;
    #pragma unroll 8
    for (int j = 0; j < 256; ++j) {
        float4 s = pts[j];                    // wave-uniform address -> bank broadcast
        float dx = s.x - xk, dy = s.y - yk;
        float d2 = fmaf(dy, dy, fmaf(dx, dx, 1e-6f));  // eps folded (att err ~1e-6*qq)
        float r = __builtin_amdgcn_sqrtf(d2);
        float h = fmaxf(0.0f, 1.0f - r);
        bool own = (__float_as_int(s.w) == t);
        rep = fmaf(own ? 0.0f : h,  s.z, rep);
        att = fmaf(own ? d2 : 0.0f, s.z, att);
    }
    int o = t * hstr + blockIdx.x;
    rep_part[o] = rep;
    att_part[o] = att;
}

// ---------------- Kernel D1: per-object reduce of heavy partials (coalesced rows)
__global__ __launch_bounds__(256) void final1(
    const float4* __restrict__ objA,
    const float4* __restrict__ objB,
    const float*  __restrict__ rep_part,
    const float*  __restrict__ att_part,
    float4* __restrict__ objC,   // (s0, valid, cnt, 0)
    int n, int nbh, int hstr)
{
    __shared__ float srep[256], satt[256];
    int k = blockIdx.x;
    int b = threadIdx.x;
    float rep = 0.f, att = 0.f;
    int o = k * hstr + b;
    if (b < nbh)        { rep += rep_part[o];        att += att_part[o]; }
    if (b + 256 < nbh)  { rep += rep_part[o + 256];  att += att_part[o + 256]; }
    srep[b] = rep; satt[b] = att;
    __syncthreads();
    for (int s = 128; s > 0; s >>= 1) {
        if (b < s) { srep[b] += srep[b + s]; satt[b] += satt[b + s]; }
        __syncthreads();
    }
    if (b == 0) {
        float4 a  = objA[k];
        float4 b4 = objB[k];
        float cnt = a.w, qa = a.z, valid = b4.z;
        float vatt = valid * satt[0] * qa / fmaxf(cnt, 1.0f);
        float vrep = valid * srep[0] * qa / fmaxf((float)n - cnt, 1.0f);
        objC[k] = make_float4(vatt + vrep + b4.y + b4.x, valid, cnt, 0.f);
    }
}

// ---------------- Kernel D2: scalar finish
__global__ __launch_bounds__(256) void final2(
    const float4* __restrict__ objC,
    const float*  __restrict__ noise_part,
    float* __restrict__ out, int n)
{
    __shared__ float4 sred[256];
    int t = threadIdx.x;
    float4 c = objC[t];
    c.w = noise_part[t];
    sred[t] = c;
    __syncthreads();
    for (int s = 128; s > 0; s >>= 1) {
        if (t < s) {
            float4 x = sred[t], y = sred[t + s];
            sred[t] = make_float4(x.x + y.x, x.y + y.y, x.z + y.z, x.w + y.w);
        }
        __syncthreads();
    }
    if (t == 0) {
        float4 r = sred[0];
        float nv = fmaxf(r.y, 1.0f);                    // n_valid
        float nnoise = fmaxf((float)n - r.z, 1.0f);     // noise count
        out[0] = r.x / nv + r.w / nnoise;
    }
}

extern "C" void kernel_launch(void* const* d_in, const int* in_sizes, int n_in,
                              void* d_out, int out_size, void* d_ws, size_t ws_size,
                              hipStream_t stream) {
    const float*  pred_beta    = (const float*)d_in[0];
    const float2* pred_ccoords = (const float2*)d_in[1];
    const float*  pred_energy  = (const float*)d_in[2];
    const float2* pred_pos     = (const float2*)d_in[3];
    const float*  pred_time    = (const float*)d_in[4];
    const float2* pred_id2     = (const float2*)d_in[5];
    const float*  t_energy     = (const float*)d_in[6];
    const float2* t_pos        = (const float2*)d_in[7];
    const float*  t_time       = (const float*)d_in[8];
    const int*    t_idx        = (const int*)d_in[10];
    int n = in_sizes[0];
    int nbh = (n + 255) / 256;          // 391 for n=100000
    int hstr = (nbh + 8) & ~7;          // padded row stride (392)

    // workspace carve (16B-aligned)
    char* base = (char*)d_ws;
    size_t off = 0;
    u64*    pk_part    = (u64*)   (base + off); off += (size_t)KOBJ * B1 * 8;    // 512 KB
    float*  cnt_part   = (float*) (base + off); off += (size_t)KOBJ * B1 * 4;    // 256 KB
    float*  den_part   = (float*) (base + off); off += (size_t)KOBJ * B1 * 4;    // 256 KB
    float*  num_part   = (float*) (base + off); off += (size_t)KOBJ * B1 * 4;    // 256 KB
    float*  noise_part = (float*) (base + off); off += 256 * 4;
    float4* objA       = (float4*)(base + off); off += KOBJ * 16;
    float4* objB       = (float4*)(base + off); off += KOBJ * 16;
    float4* objC       = (float4*)(base + off); off += KOBJ * 16;
    float*  rep_part   = (float*) (base + off); off += (size_t)KOBJ * hstr * 4;  // ~400 KB
    float*  att_part   = (float*) (base + off); off += (size_t)KOBJ * hstr * 4;

    partials<<<B1, 256, 0, stream>>>(pred_beta, pred_energy, pred_pos, pred_time,
                                     pred_id2, t_energy, t_pos, t_time, t_idx,
                                     pk_part, cnt_part, den_part, num_part, noise_part, n);
    merge<<<KOBJ, 256, 0, stream>>>(pred_ccoords, pk_part, cnt_part, den_part, num_part,
                                    objA, objB);
    heavy<<<nbh, 256, 0, stream>>>(pred_beta, pred_ccoords, t_idx, objA,
                                   rep_part, att_part, n, hstr);
    final1<<<KOBJ, 256, 0, stream>>>(objA, objB, rep_part, att_part, objC, n, nbh, hstr);
    final2<<<1, 256, 0, stream>>>(objC, noise_part, (float*)d_out, n);
}